// Round 6
// baseline (894.821 us; speedup 1.0000x reference)
//
#include <hip/hip_runtime.h>

// LSTM B=2048, T=1024, H=50. Round 6: 4-wave block, 1 barrier/step,
// per-lane epilogue with 4-way ILP, x/bias folded into the MFMA.
//
// grid=128, block=256 (4 waves), BW=16 batches/block.
// A = W' (permuted gate rows n'=4j+g) f16 hi+lo, resident in VGPRs.
//   K layout: k<50 = W_hh; k=50,51 = W_ih (x enters as x_hi+x_lo);
//   k=52 = combined bias (B row = 1.0); k>52 = 0.
// B = h^T from LDS (row b: [k] f16, stride KP=72 -> uniform bank spread).
// Wave w owns tiles {w, w+4, w+8, (w==0: 12)}; lane (kq,L15) of tile i holds
// gates {i,f,g,o} of (unit j=4*tile+kq, batch L15) in acc[0..3] -> pure
// per-lane epilogue, c-state in regs, 4 independent chains per lane.
// Two 2-deep MFMA chains (hi/lo) per tile, summed.
// One barrier per step (h double-buffered). Tile-12 pad units j=50,51 skip
// their h-write (those k-slots hold x_hi/x_lo!).

#define H     50
#define TT    1024
#define BATCH 2048
#define BW    16
#define KP    72      // f16 per hbuf row (144 B -> uniform bank spread)
#define KX_HI 50
#define KX_LO 51
#define KONE  52

typedef float    f32x4 __attribute__((ext_vector_type(4)));
typedef _Float16 f16x8 __attribute__((ext_vector_type(8)));

__device__ __forceinline__ float fast_sigmoid(float x) {
    float e = __builtin_amdgcn_exp2f(-1.4426950408889634f * x);
    return __builtin_amdgcn_rcpf(1.0f + e);
}
__device__ __forceinline__ float fast_tanh(float x) {
    float e = __builtin_amdgcn_exp2f(2.8853900817779268f * x);
    return 1.0f - 2.0f * __builtin_amdgcn_rcpf(e + 1.0f);
}

__global__ __launch_bounds__(256, 1) void lstm_kernel(
    const float* __restrict__ x,      // [B, T]
    const float* __restrict__ W_ih,   // [200]
    const float* __restrict__ W_hh,   // [200, 50]
    const float* __restrict__ b_ih,   // [200]
    const float* __restrict__ b_hh,   // [200]
    const float* __restrict__ W_lin,  // [50]
    const float* __restrict__ b_lin,  // [1]
    float* __restrict__ out)          // [B]
{
    __shared__ _Float16 hb[2][BW][KP];   // h^T + x/one slots, double-buffered
    __shared__ float red[16][BW];        // head reduction scratch

    const int tid  = threadIdx.x;
    const int wave = tid >> 6;
    const int lane = tid & 63;
    const int L15  = lane & 15;
    const int kq   = lane >> 4;
    const int b0   = blockIdx.x * BW;

    const int ntiles = (wave == 0) ? 4 : 3;   // wave w: tiles w+4i

    // ---- A fragments: permuted W' rows + x/bias columns, f16 hi+lo ----
    // A[m = L15][k = kf*32 + kq*8 + e] of tile -> row 16*tile+L15 = 4j+g
    f16x8 Ahi[4][2], Alo[4][2];
    #pragma unroll
    for (int i = 0; i < 4; ++i) {
        if (i >= ntiles) break;
        const int t  = wave + 4 * i;
        const int m  = t * 16 + L15;
        const int jm = m >> 2, gm = m & 3;
        #pragma unroll
        for (int kf = 0; kf < 2; ++kf) {
            f16x8 vh, vl;
            #pragma unroll
            for (int e = 0; e < 8; ++e) {
                int k = kf * 32 + kq * 8 + e;
                float w = 0.f;
                if (jm < H) {
                    if (k < H)                        w = W_hh[(gm * H + jm) * H + k];
                    else if (k == KX_HI || k == KX_LO) w = W_ih[gm * H + jm];
                    else if (k == KONE)               w = b_ih[gm * H + jm] + b_hh[gm * H + jm];
                }
                _Float16 h16 = (_Float16)w;
                vh[e] = h16;
                vl[e] = (_Float16)(w - (float)h16);
            }
            Ahi[i][kf] = vh; Alo[i][kf] = vl;
        }
    }

    // ---- head weights per pair ----
    float wlin[4];
    #pragma unroll
    for (int i = 0; i < 4; ++i) {
        int j = 4 * (wave + 4 * i) + kq;
        wlin[i] = (i < ntiles && j < H) ? W_lin[j] : 0.f;
    }

    // ---- init: zero hb, then seed x(t=0)/one slots in buffer 0 ----
    for (int idx = tid; idx < 2 * BW * KP; idx += 256)
        ((_Float16*)hb)[idx] = (_Float16)0.f;
    __syncthreads();
    if (tid < BW) {
        float xv = x[(size_t)(b0 + tid) * TT];
        _Float16 xh = (_Float16)xv;
        hb[0][tid][KX_HI] = xh;
        hb[0][tid][KX_LO] = (_Float16)(xv - (float)xh);
        hb[0][tid][KONE]  = (_Float16)1.0f;
    }

    // x prefetch: lane reads x[b0+L15][.]; only wave 0 consumes.
    const float* xrow = x + (size_t)(b0 + L15) * TT;
    float4 xq  = *(const float4*)(xrow);       // block covering idx 0..3
    float4 xq2 = *(const float4*)(xrow + 4);   // next block

    float c[4]    = {0.f, 0.f, 0.f, 0.f};
    float hlast[4] = {0.f, 0.f, 0.f, 0.f};
    __syncthreads();

    for (int t = 0; t < TT; ++t) {
        // ---- B fragments from LDS ----
        const _Float16* hp = &hb[t & 1][L15][0];
        f16x8 B0 = *(const f16x8*)(hp + kq * 8);
        f16x8 B1 = *(const f16x8*)(hp + 32 + kq * 8);

        // ---- MFMA: two 2-deep chains per tile ----
        f32x4 acc[4];
        #pragma unroll
        for (int i = 0; i < 4; ++i) {
            if (i >= ntiles) break;
            f32x4 z = {0.f, 0.f, 0.f, 0.f};
            f32x4 aH = __builtin_amdgcn_mfma_f32_16x16x32_f16(Ahi[i][0], B0, z, 0, 0, 0);
            aH = __builtin_amdgcn_mfma_f32_16x16x32_f16(Ahi[i][1], B1, aH, 0, 0, 0);
            f32x4 aL = __builtin_amdgcn_mfma_f32_16x16x32_f16(Alo[i][0], B0, z, 0, 0, 0);
            aL = __builtin_amdgcn_mfma_f32_16x16x32_f16(Alo[i][1], B1, aL, 0, 0, 0);
            acc[i] = aH + aL;
        }

        // ---- x/one slots of next buffer (wave 0 only) ----
        const int idx = t + 1;
        if ((idx & 3) == 0) {          // rotate x prefetch
            xq = xq2;
            int o = idx + 4; if (o > TT - 4) o = TT - 4;
            xq2 = *(const float4*)(xrow + o);
        }
        if (wave == 0) {
            const float xv = ((const float*)&xq)[idx & 3];
            _Float16 xh = (_Float16)xv;
            if (kq == 0)      hb[idx & 1][L15][KX_HI] = xh;
            else if (kq == 1) hb[idx & 1][L15][KX_LO] = (_Float16)(xv - (float)xh);
            else if (kq == 2) hb[idx & 1][L15][KONE]  = (_Float16)1.0f;
        }

        // ---- per-lane epilogue: 4 independent pairs ----
        #pragma unroll
        for (int i = 0; i < 4; ++i) {
            if (i >= ntiles) break;
            float i_ = fast_sigmoid(acc[i][0]);
            float f_ = fast_sigmoid(acc[i][1]);
            float g_ = fast_tanh   (acc[i][2]);
            float o_ = fast_sigmoid(acc[i][3]);
            c[i] = __builtin_fmaf(f_, c[i], i_ * g_);
            float h = o_ * fast_tanh(c[i]);
            hlast[i] = h;
            const int j = 4 * (wave + 4 * i) + kq;
            if (j < H)                      // pad units j=50,51 must NOT
                hb[idx & 1][L15][j] = (_Float16)h;   // clobber x slots
        }
        __syncthreads();   // new h + x visible for next step
    }

    // ---- head: out[b] = b_lin + sum_j W_lin[j] * h[j][b] ----
    float local = 0.f;
    #pragma unroll
    for (int i = 0; i < 4; ++i) local += wlin[i] * hlast[i];
    red[wave * 4 + kq][L15] = local;
    __syncthreads();
    if (tid < BW) {
        float s = b_lin[0];
        #pragma unroll
        for (int r = 0; r < 16; ++r) s += red[r][tid];
        out[b0 + tid] = s;
    }
}

extern "C" void kernel_launch(void* const* d_in, const int* in_sizes, int n_in,
                              void* d_out, int out_size, void* d_ws, size_t ws_size,
                              hipStream_t stream) {
    const float* x     = (const float*)d_in[0];
    const float* W_ih  = (const float*)d_in[1];
    const float* W_hh  = (const float*)d_in[2];
    const float* b_ih  = (const float*)d_in[3];
    const float* b_hh  = (const float*)d_in[4];
    const float* W_lin = (const float*)d_in[5];
    const float* b_lin = (const float*)d_in[6];
    float* out = (float*)d_out;

    dim3 grid(BATCH / BW);    // 128 blocks x 16 batches
    dim3 block(256);          // 4 waves
    lstm_kernel<<<grid, block, 0, stream>>>(x, W_ih, W_hh, b_ih, b_hh,
                                            W_lin, b_lin, out);
}

// Round 7
// 467.415 us; speedup vs baseline: 1.9144x; 1.9144x over previous
//
#include <hip/hip_runtime.h>

// LSTM B=2048, T=1024, H=50. Round 7: minimize the per-step serial chain.
// Wall time = 1024 * (one block's step chain); device fill is irrelevant.
//
// grid=256, BW=8 batches/block, block=448 (7 waves, 1.75/SIMD for hiding).
// Wave w owns tiles t0=2w, t1=2w+1 of the 13 permuted gate-row tiles
// (rows n'=4j+g, g=PyTorch i,f,g,o). A = W' f16 hi+lo resident in VGPRs.
// h^T stored TWICE in LDS: cols 0-7 = batches 0-7, cols 8-15 = same batches
// (shifted copy) -> tile t1's D cols 8-15 hold batches 0-7 directly, so
// lane (kq, L15) takes acc0 (L15<8) or acc1 (L15>=8): unit j=8w+kq+(L15<8?0:4),
// batch bl=L15&7, gates i,f,g,o = acc[0..3]. Pure per-lane epilogue, c in reg.
// Trans issue/SIMD halves vs R3 (pairs/block 832->448). One barrier/step.
// x fully staged in LDS upfront -> no global ops (no vmcnt drains) in-loop.

#define H     50
#define TT    1024
#define BATCH 2048
#define BW    8
#define NTHR  448     // 7 waves
#define KP    72      // f16 per hb row (144 B -> stride 4 banks, ~2-way max)
#define XP    1025    // padded x row stride (f32) -> b+t bank spread

typedef float    f32x4 __attribute__((ext_vector_type(4)));
typedef _Float16 f16x8 __attribute__((ext_vector_type(8)));

__device__ __forceinline__ float fast_sigmoid(float x) {
    float e = __builtin_amdgcn_exp2f(-1.4426950408889634f * x);
    return __builtin_amdgcn_rcpf(1.0f + e);
}
__device__ __forceinline__ float fast_tanh(float x) {
    float e = __builtin_amdgcn_exp2f(2.8853900817779268f * x);
    return 1.0f - 2.0f * __builtin_amdgcn_rcpf(e + 1.0f);
}

__global__ __launch_bounds__(NTHR, 1) void lstm_kernel(
    const float* __restrict__ x,      // [B, T]
    const float* __restrict__ W_ih,   // [200]
    const float* __restrict__ W_hh,   // [200, 50]
    const float* __restrict__ b_ih,   // [200]
    const float* __restrict__ b_hh,   // [200]
    const float* __restrict__ W_lin,  // [50]
    const float* __restrict__ b_lin,  // [1]
    float* __restrict__ out)          // [B]
{
    __shared__ _Float16 hb[2][16][KP];   // h^T dbl-buf; cols 8-15 = shifted copy
    __shared__ float    xs[BW * XP];     // all x for this block's 8 batches
    __shared__ float    redH[H][BW];     // head reduction

    const int tid  = threadIdx.x;
    const int wave = tid >> 6;
    const int lane = tid & 63;
    const int L15  = lane & 15;
    const int kq   = lane >> 4;
    const int bl   = L15 & 7;
    const int b0   = blockIdx.x * BW;

    const int t0 = 2 * wave;             // tiles t0, t0+1 (wave 6: 12, 13-pad)

    // ---- A fragments: permuted W' rows, f16 hi+lo, resident in VGPRs ----
    // tile tt: A[m=L15][k=kf*32+kq*8+e], global row m=16*(t0+tt)+L15 = 4j+g
    f16x8 Ahi[2][2], Alo[2][2];
    #pragma unroll
    for (int tt = 0; tt < 2; ++tt) {
        const int m  = (t0 + tt) * 16 + L15;
        const int jm = m >> 2, gm = m & 3;
        #pragma unroll
        for (int kf = 0; kf < 2; ++kf) {
            f16x8 vh, vl;
            #pragma unroll
            for (int e = 0; e < 8; ++e) {
                int k = kf * 32 + kq * 8 + e;
                float w = (jm < H && k < H) ? W_hh[(gm * H + jm) * H + k] : 0.f;
                _Float16 h16 = (_Float16)w;
                vh[e] = h16;
                vl[e] = (_Float16)(w - (float)h16);
            }
            Ahi[tt][kf] = vh; Alo[tt][kf] = vl;
        }
    }

    // ---- per-lane pair: unit j, batch bl ----
    const int  j  = 4 * t0 + kq + ((L15 >> 3) << 2);   // +4 for upper half
    const bool jv = (j < H);
    float wih[4], bias[4];
    #pragma unroll
    for (int g = 0; g < 4; ++g) {
        wih[g]  = jv ? W_ih[g * H + j] : 0.f;
        bias[g] = jv ? (b_ih[g * H + j] + b_hh[g * H + j]) : 0.f;
    }
    const float wlin = jv ? W_lin[j] : 0.f;

    // ---- stage x (coalesced), zero hb (h0=0; k>=50 stays 0 = K-pad) ----
    for (int i = tid; i < BW * TT; i += NTHR) {
        int row = i >> 10, col = i & 1023;
        xs[row * XP + col] = x[(size_t)(b0 + row) * TT + col];
    }
    for (int i = tid; i < 2 * 16 * KP; i += NTHR)
        ((_Float16*)hb)[i] = (_Float16)0.f;

    float c = 0.f, hlast = 0.f;
    __syncthreads();

    for (int t = 0; t < TT; ++t) {
        // ---- B fragments (shared by both tiles; shift baked into cols) ----
        const _Float16* hp = &hb[t & 1][L15][0];
        f16x8 B0 = *(const f16x8*)(hp + kq * 8);        // k 0..31
        f16x8 B1 = *(const f16x8*)(hp + 32 + kq * 8);   // k 32..63

        // ---- 8 MFMAs: 4 independent 2-deep chains ----
        f32x4 z = {0.f, 0.f, 0.f, 0.f};
        f32x4 aH0 = __builtin_amdgcn_mfma_f32_16x16x32_f16(Ahi[0][0], B0, z, 0, 0, 0);
        f32x4 aL0 = __builtin_amdgcn_mfma_f32_16x16x32_f16(Alo[0][0], B0, z, 0, 0, 0);
        f32x4 aH1 = __builtin_amdgcn_mfma_f32_16x16x32_f16(Ahi[1][0], B0, z, 0, 0, 0);
        f32x4 aL1 = __builtin_amdgcn_mfma_f32_16x16x32_f16(Alo[1][0], B0, z, 0, 0, 0);
        aH0 = __builtin_amdgcn_mfma_f32_16x16x32_f16(Ahi[0][1], B1, aH0, 0, 0, 0);
        aL0 = __builtin_amdgcn_mfma_f32_16x16x32_f16(Alo[0][1], B1, aL0, 0, 0, 0);
        aH1 = __builtin_amdgcn_mfma_f32_16x16x32_f16(Ahi[1][1], B1, aH1, 0, 0, 0);
        aL1 = __builtin_amdgcn_mfma_f32_16x16x32_f16(Alo[1][1], B1, aL1, 0, 0, 0);
        f32x4 acc0 = aH0 + aL0;
        f32x4 acc1 = aH1 + aL1;

        // ---- select this lane's tile, add x/bias, activate ----
        const bool lo = (L15 < 8);
        const float xv = xs[bl * XP + t];
        float g0 = (lo ? acc0[0] : acc1[0]) + __builtin_fmaf(wih[0], xv, bias[0]);
        float g1 = (lo ? acc0[1] : acc1[1]) + __builtin_fmaf(wih[1], xv, bias[1]);
        float g2 = (lo ? acc0[2] : acc1[2]) + __builtin_fmaf(wih[2], xv, bias[2]);
        float g3 = (lo ? acc0[3] : acc1[3]) + __builtin_fmaf(wih[3], xv, bias[3]);
        float i_ = fast_sigmoid(g0);
        float f_ = fast_sigmoid(g1);
        float g_ = fast_tanh(g2);
        float o_ = fast_sigmoid(g3);
        c = __builtin_fmaf(f_, c, i_ * g_);
        float h = o_ * fast_tanh(c);
        hlast = h;

        const int nb = (t + 1) & 1;
        if (jv) {
            _Float16 hh = (_Float16)h;
            hb[nb][bl][j]     = hh;     // primary copy   (tile t0 lanes)
            hb[nb][bl + 8][j] = hh;     // shifted copy   (tile t1 lanes)
        }
        __syncthreads();   // new h visible; buffer (t+1)&1 WAR-safe by dbl-buf
    }

    // ---- head: out[b] = b_lin + sum_j W_lin[j] * h[j][b] ----
    if (jv) redH[j][bl] = wlin * hlast;
    __syncthreads();
    if (tid < BW) {
        float s = b_lin[0];
        #pragma unroll 10
        for (int jj = 0; jj < H; ++jj) s += redH[jj][tid];
        out[b0 + tid] = s;
    }
}

extern "C" void kernel_launch(void* const* d_in, const int* in_sizes, int n_in,
                              void* d_out, int out_size, void* d_ws, size_t ws_size,
                              hipStream_t stream) {
    const float* x     = (const float*)d_in[0];
    const float* W_ih  = (const float*)d_in[1];
    const float* W_hh  = (const float*)d_in[2];
    const float* b_ih  = (const float*)d_in[3];
    const float* b_hh  = (const float*)d_in[4];
    const float* W_lin = (const float*)d_in[5];
    const float* b_lin = (const float*)d_in[6];
    float* out = (float*)d_out;

    dim3 grid(BATCH / BW);    // 256 blocks, 1 per CU
    dim3 block(NTHR);         // 7 waves
    lstm_kernel<<<grid, block, 0, stream>>>(x, W_ih, W_hh, b_ih, b_hh,
                                            W_lin, b_lin, out);
}

// Round 9
// 389.167 us; speedup vs baseline: 2.2993x; 1.2011x over previous
//
#include <hip/hip_runtime.h>

// LSTM B=2048, T=1024, H=50. Round 9: R8 design + 2 bug fixes.
//   FIX 1: head write guard was `jv && L15<8`, dropping the tile-t1 units
//          (odd j-quads) -> redH rows uninitialized -> absmax 12.3. Now `jv`.
//   FIX 2: x prefetch rotated AFTER the read at idx%4==0 -> stale x every
//          4th step. Now rotate-before-read (as in R6/R7).
//
// grid=256 (1 block/CU), BW=8 batches, block=448 (7 waves, 1.75/SIMD).
// Wave w owns permuted-gate-row tiles t0=2w, t0+1 (rows n'=4j+g), sharing one
// B-read via the dual h-copy trick (cols 0-7 = batches, 8-15 = same).
// A = scaled W' in SINGLE f16 (numerics test: predicted absmax ~1e-3),
// resident in VGPRs.
//   Row scale: i,f,o rows x -log2(e)  -> sigmoid(z) = rcp(1+exp2(z'))
//              g rows     x +2*log2(e) -> tanh(z)  = 1-2*rcp(1+exp2(z'))
//   K slots: 0-49 = W_hh | 50: wih_hi (B=x_hi) | 51: wih_hi (B=x_lo)
//            52: wih_lo (B=x_hi) | 53: bias_hi (B=1) | 54: bias_lo (B=1)
//   -> gates arrive from MFMA fully biased+scaled; epilogue = sel + trans.
// Per step: 2 ds_read_b128 + 4 MFMA (two 2-deep chains) + 4 cndmask +
// 5 exp2 + 5 rcp + ~14 VALU + 2 ds_write_b16 + 1 barrier.

#define H     50
#define TT    1024
#define BATCH 2048
#define BW    8
#define NTHR  448     // 7 waves
#define KP    72      // f16 per hb row (36 words -> 2-way banks max on b128)
#define KX_HI 50
#define KX_LO 51
#define KX_H2 52
#define KB_HI 53
#define KB_LO 54

typedef float    f32x4 __attribute__((ext_vector_type(4)));
typedef _Float16 f16x8 __attribute__((ext_vector_type(8)));

__global__ __launch_bounds__(NTHR, 1) void lstm_kernel(
    const float* __restrict__ x,      // [B, T]
    const float* __restrict__ W_ih,   // [200]
    const float* __restrict__ W_hh,   // [200, 50]
    const float* __restrict__ b_ih,   // [200]
    const float* __restrict__ b_hh,   // [200]
    const float* __restrict__ W_lin,  // [50]
    const float* __restrict__ b_lin,  // [1]
    float* __restrict__ out)          // [B]
{
    __shared__ _Float16 hb[2][16][KP];   // h^T + x/bias cols, double-buffered
    __shared__ float    redH[H][BW];     // head reduction

    const int tid  = threadIdx.x;
    const int wave = tid >> 6;
    const int lane = tid & 63;
    const int L15  = lane & 15;
    const int kq   = lane >> 4;
    const int bl   = L15 & 7;
    const int b0   = blockIdx.x * BW;

    const int t0 = 2 * wave;             // tiles t0, t0+1 (wave 6: 12, 13=pad)

    const float LOG2E  = 1.4426950408889634f;
    const float LOG2E2 = 2.8853900817779268f;

    // ---- A fragments: scaled permuted W' rows, single f16, in VGPRs ----
    // tile tt: A[m=L15][k=kf*32+kq*8+e], global row m=16*(t0+tt)+L15 = 4j+g
    f16x8 A[2][2];
    #pragma unroll
    for (int tt = 0; tt < 2; ++tt) {
        const int m  = (t0 + tt) * 16 + L15;
        const int jm = m >> 2, gm = m & 3;
        const float s = (gm == 2) ? LOG2E2 : -LOG2E;   // g-gate vs i,f,o
        float swih = 0.f, sbias = 0.f;
        if (jm < H) {
            swih  = s * W_ih[gm * H + jm];
            sbias = s * (b_ih[gm * H + jm] + b_hh[gm * H + jm]);
        }
        const _Float16 whi = (_Float16)swih;
        const _Float16 wlo = (_Float16)(swih - (float)whi);
        const _Float16 bhi = (_Float16)sbias;
        const _Float16 blo = (_Float16)(sbias - (float)bhi);
        #pragma unroll
        for (int kf = 0; kf < 2; ++kf) {
            f16x8 v;
            #pragma unroll
            for (int e = 0; e < 8; ++e) {
                const int k = kf * 32 + kq * 8 + e;
                _Float16 val = (_Float16)0.f;
                if (jm < H) {
                    if (k < H)            val = (_Float16)(s * W_hh[(gm * H + jm) * H + k]);
                    else if (k == KX_HI)  val = whi;
                    else if (k == KX_LO)  val = whi;
                    else if (k == KX_H2)  val = wlo;
                    else if (k == KB_HI)  val = bhi;
                    else if (k == KB_LO)  val = blo;
                }
                v[e] = val;
            }
            A[tt][kf] = v;
        }
    }

    // ---- per-lane pair: unit j, batch bl ----
    const int  j  = 4 * t0 + kq + ((L15 >> 3) << 2);   // upper col-half -> +4
    const bool jv = (j < H);
    const float wlin = jv ? W_lin[j] : 0.f;

    // ---- init LDS: zero hb; constant-1 slots (both buffers); x(0) slots ----
    for (int i = tid; i < 2 * 16 * KP; i += NTHR)
        ((_Float16*)hb)[i] = (_Float16)0.f;
    __syncthreads();
    if (tid < 32) {                      // buf = tid>>4, col = tid&15
        hb[tid >> 4][tid & 15][KB_HI] = (_Float16)1.0f;
        hb[tid >> 4][tid & 15][KB_LO] = (_Float16)1.0f;
    } else if (tid < 48) {               // x(t=0) into buffer 0
        const int col = tid & 15;
        const float xv = x[(size_t)(b0 + (col & 7)) * TT];
        const _Float16 xh = (_Float16)xv;
        hb[0][col][KX_HI] = xh;
        hb[0][col][KX_LO] = (_Float16)(xv - (float)xh);
        hb[0][col][KX_H2] = xh;
    }

    // ---- x prefetch (wave 0 only consumes/loads) ----
    const float* xrow = x + (size_t)(b0 + bl) * TT;
    float4 xq = {0,0,0,0}, xq2 = {0,0,0,0};
    if (wave == 0) {
        xq  = *(const float4*)(xrow);
        xq2 = *(const float4*)(xrow + 4);
    }

    float c = 0.f, hlast = 0.f;
    __syncthreads();

    for (int t = 0; t < TT; ++t) {
        // ---- B fragments (shared by both tiles via dual h-copy) ----
        const _Float16* hp = &hb[t & 1][L15][0];
        f16x8 B0 = *(const f16x8*)(hp + kq * 8);        // k 0..31
        f16x8 B1 = *(const f16x8*)(hp + 32 + kq * 8);   // k 32..63

        // ---- 4 MFMAs: two independent 2-deep chains ----
        f32x4 z = {0.f, 0.f, 0.f, 0.f};
        f32x4 a0 = __builtin_amdgcn_mfma_f32_16x16x32_f16(A[0][0], B0, z, 0, 0, 0);
        f32x4 a1 = __builtin_amdgcn_mfma_f32_16x16x32_f16(A[1][0], B0, z, 0, 0, 0);
        a0 = __builtin_amdgcn_mfma_f32_16x16x32_f16(A[0][1], B1, a0, 0, 0, 0);
        a1 = __builtin_amdgcn_mfma_f32_16x16x32_f16(A[1][1], B1, a1, 0, 0, 0);

        const int idx = t + 1;
        const int nb  = idx & 1;

        // ---- wave 0: x slots of next buffer (rotate BEFORE read — FIX 2) ----
        if (wave == 0) {
            if ((idx & 3) == 0) {
                xq = xq2;
                int o = idx + 4; if (o > TT - 4) o = TT - 4;
                xq2 = *(const float4*)(xrow + o);
            }
            const float xv = ((const float*)&xq)[idx & 3];
            if (kq < 3) {
                const _Float16 xh = (_Float16)xv;
                const _Float16 xl = (_Float16)(xv - (float)xh);
                const int slot = (kq == 0) ? KX_HI : (kq == 1) ? KX_LO : KX_H2;
                hb[nb][L15][slot] = (kq == 1) ? xl : xh;
            }
        }

        // ---- per-lane epilogue: gates arrive scaled+biased from MFMA ----
        const bool lo = (L15 < 8);
        const float zi = lo ? a0[0] : a1[0];
        const float zf = lo ? a0[1] : a1[1];
        const float zg = lo ? a0[2] : a1[2];
        const float zo = lo ? a0[3] : a1[3];
        const float i_ = __builtin_amdgcn_rcpf(1.0f + __builtin_amdgcn_exp2f(zi));
        const float f_ = __builtin_amdgcn_rcpf(1.0f + __builtin_amdgcn_exp2f(zf));
        const float o_ = __builtin_amdgcn_rcpf(1.0f + __builtin_amdgcn_exp2f(zo));
        const float g_ = __builtin_fmaf(-2.0f,
            __builtin_amdgcn_rcpf(1.0f + __builtin_amdgcn_exp2f(zg)), 1.0f);
        c = __builtin_fmaf(f_, c, i_ * g_);
        const float tc_ = __builtin_fmaf(-2.0f,
            __builtin_amdgcn_rcpf(1.0f + __builtin_amdgcn_exp2f(LOG2E2 * c)), 1.0f);
        const float h = o_ * tc_;
        hlast = h;

        if (jv) {                        // pad units j=50,51 must not clobber
            const _Float16 hh = (_Float16)h;
            hb[nb][bl][j]     = hh;      // primary copy  (tile t0 lanes)
            hb[nb][bl + 8][j] = hh;      // shifted copy  (tile t1 lanes)
        }
        __syncthreads();
    }

    // ---- head: out[b] = b_lin + sum_j W_lin[j] * h[j][b]  (FIX 1: all jv) ----
    if (jv) redH[j][bl] = wlin * hlast;
    __syncthreads();
    if (tid < BW) {
        float s = b_lin[0];
        #pragma unroll 10
        for (int jj = 0; jj < H; ++jj) s += redH[jj][tid];
        out[b0 + tid] = s;
    }
}

extern "C" void kernel_launch(void* const* d_in, const int* in_sizes, int n_in,
                              void* d_out, int out_size, void* d_ws, size_t ws_size,
                              hipStream_t stream) {
    const float* x     = (const float*)d_in[0];
    const float* W_ih  = (const float*)d_in[1];
    const float* W_hh  = (const float*)d_in[2];
    const float* b_ih  = (const float*)d_in[3];
    const float* b_hh  = (const float*)d_in[4];
    const float* W_lin = (const float*)d_in[5];
    const float* b_lin = (const float*)d_in[6];
    float* out = (float*)d_out;

    dim3 grid(BATCH / BW);    // 256 blocks, 1 per CU
    dim3 block(NTHR);         // 7 waves
    lstm_kernel<<<grid, block, 0, stream>>>(x, W_ih, W_hh, b_ih, b_hh,
                                            W_lin, b_lin, out);
}